// Round 1
// baseline (421.526 us; speedup 1.0000x reference)
//
#include <hip/hip_runtime.h>
#include <hip/hip_bf16.h>

#define NROW 8192
#define FIN  512
#define FOUT 64
#define NHEAD 4

constexpr float LOG2E = 1.44269504088896f;

typedef float f32x4 __attribute__((ext_vector_type(4)));
typedef __bf16 bf16x8 __attribute__((ext_vector_type(8)));

// ---------------------------------------------------------------------------
// K1: h[hd][n][o] = sum_f x[n][f] * W[hd][f][o]   (f32 accumulate)
// emits: hT (bf16, [NHEAD][FOUT][NROW]  -- transposed for MFMA A-frags)
//        f1c = (h . a1) * LOG2E   [NHEAD][NROW]
//        f2c = (h . a2) * LOG2E   [NHEAD][NROW]
// block = 256 threads handles 8 rows of x, all heads/outputs.
// thread t -> (hd = t>>6, oc = (t>>3)&7, r = t&7); outputs o = oc*8..oc*8+7
// ---------------------------------------------------------------------------
__global__ __launch_bounds__(256) void gat_proj(
    const float* __restrict__ x, const float* __restrict__ W,
    const float* __restrict__ a1, const float* __restrict__ a2,
    __hip_bfloat16* __restrict__ hT, float* __restrict__ f1,
    float* __restrict__ f2)
{
  __shared__ float xs[8][516];            // +4 pad breaks bank aliasing
  const int t  = threadIdx.x;
  const int n0 = blockIdx.x * 8;

  // stage x rows (coalesced float4)
#pragma unroll
  for (int i = 0; i < 4; ++i) {
    int v = i * 256 + t;                  // 1024 float4 total
    int r = v >> 7;                       // 128 float4 per row
    int c = (v & 127) << 2;
    *(f32x4*)(&xs[r][c]) = *(const f32x4*)(x + (n0 + r) * FIN + c);
  }
  __syncthreads();

  const int hd = t >> 6;
  const int oc = (t >> 3) & 7;
  const int r  = t & 7;
  const float* wp = W + hd * (FIN * FOUT) + oc * 8;

  float acc[8];
#pragma unroll
  for (int j = 0; j < 8; ++j) acc[j] = 0.f;

#pragma unroll 4
  for (int k = 0; k < FIN; ++k) {
    float xv = xs[r][k];
    f32x4 w0 = *(const f32x4*)(wp + k * FOUT);
    f32x4 w1 = *(const f32x4*)(wp + k * FOUT + 4);
#pragma unroll
    for (int j = 0; j < 4; ++j) acc[j]     = fmaf(xv, w0[j], acc[j]);
#pragma unroll
    for (int j = 0; j < 4; ++j) acc[4 + j] = fmaf(xv, w1[j], acc[4 + j]);
  }

  // transposed bf16 h for the attention kernel's A-fragments
#pragma unroll
  for (int j = 0; j < 8; ++j)
    hT[(hd * FOUT + oc * 8 + j) * NROW + n0 + r] = __float2bfloat16(acc[j]);

  // f1/f2 partials, reduce over oc (lane bits 3..5 within the wave)
  float p1 = 0.f, p2 = 0.f;
#pragma unroll
  for (int j = 0; j < 8; ++j) {
    p1 = fmaf(acc[j], a1[hd * FOUT + oc * 8 + j], p1);
    p2 = fmaf(acc[j], a2[hd * FOUT + oc * 8 + j], p2);
  }
#pragma unroll
  for (int off = 8; off < 64; off <<= 1) {
    p1 += __shfl_xor(p1, off);
    p2 += __shfl_xor(p2, off);
  }
  if (oc == 0) {
    f1[hd * NROW + n0 + r] = p1 * LOG2E;
    f2[hd * NROW + n0 + r] = p2 * LOG2E;
  }
}

// ---------------------------------------------------------------------------
// K3: masked-exp attention + PV via MFMA, no max subtraction (scores bounded).
//   P[n][m] = adj[n][m] ? exp2( lrelu_scaled(f1c[n] + f2c[m]) ) : 0
//   out[n][hd*64+o] = sigmoid( (sum_m P*hT[o][m]) / (sum_m P) )
// grid = 256 blocks (32 rows each) x 512 threads = 8 waves
//   wave wid: head = wid&3, mhalf = wid>>2 (m-chunk 0..31 / 32..63 of iter)
// MFMA 16x16x32_bf16: A = hT rows (output cols), B = P (cols = n), +ones-A
// for the softmax denominator. Lane: il=lane&15, kg=lane>>4.
// ---------------------------------------------------------------------------
__global__ __launch_bounds__(512, 2) void gat_attn(
    const int* __restrict__ adj, const __hip_bfloat16* __restrict__ hTg,
    const float* __restrict__ f1, const float* __restrict__ f2,
    float* __restrict__ out)
{
  const int tid   = threadIdx.x;
  const int wid   = tid >> 6;
  const int lane  = tid & 63;
  const int head  = wid & 3;
  const int mhalf = wid >> 2;
  const int il    = lane & 15;
  const int kg    = lane >> 4;
  const int n0    = blockIdx.x * 32;

  __shared__ unsigned int lmask[2][32][2];   // [buf][row][word32]
  __shared__ float ebuf[NHEAD][64][40];      // epilogue combine (40 KB)

  const float f1a = f1[head * NROW + n0 + il];
  const float f1b = f1[head * NROW + n0 + 16 + il];
  const float* f2p = f2 + head * NROW;
  const __hip_bfloat16* hT = hTg + head * (FOUT * NROW);

  f32x4 acc[5][2];
#pragma unroll
  for (int c = 0; c < 5; ++c)
#pragma unroll
    for (int j = 0; j < 2; ++j) {
      f32x4 z = {0.f, 0.f, 0.f, 0.f};
      acc[c][j] = z;
    }

  bf16x8 ones;
#pragma unroll
  for (int e = 0; e < 8; ++e) ones[e] = (__bf16)1.0f;

  // adj staging: wave wid owns local rows wid*4 .. wid*4+3, 64 cols per iter.
  const int arow = n0 + wid * 4;
  int adjv[2][4];
#pragma unroll
  for (int it = 0; it < 2; ++it)
#pragma unroll
    for (int b = 0; b < 4; ++b)
      adjv[it][b] = adj[(long)(arow + b) * NROW + it * 64 + lane];

  for (int it = 0; it < NROW / 64; ++it) {
    const int buf = it & 1;
#pragma unroll
    for (int b = 0; b < 4; ++b) {
      unsigned long long bal = __ballot(adjv[buf][b] != 0);
      if (lane == 0) {
        lmask[buf][wid * 4 + b][0] = (unsigned int)bal;
        lmask[buf][wid * 4 + b][1] = (unsigned int)(bal >> 32);
      }
    }
    __syncthreads();

    // prefetch adj two iterations ahead (hide ~900cy HBM latency)
    if (it + 2 < NROW / 64) {
#pragma unroll
      for (int b = 0; b < 4; ++b)
        adjv[buf][b] = adj[(long)(arow + b) * NROW + (it + 2) * 64 + lane];
    }

    const int m0 = it * 64 + mhalf * 32;
    const int mk = m0 + kg * 8;

    f32x4 f2lo = *(const f32x4*)(f2p + mk);
    f32x4 f2hi = *(const f32x4*)(f2p + mk + 4);

    bf16x8 af[4];
#pragma unroll
    for (int c = 0; c < 4; ++c)
      af[c] = *(const bf16x8*)(hT + (c * 16 + il) * NROW + mk);

    unsigned int w0 = lmask[buf][il][mhalf] >> (kg * 8);
    unsigned int w1 = lmask[buf][16 + il][mhalf] >> (kg * 8);

    float p0[8], p1v[8];
#pragma unroll
    for (int e = 0; e < 8; ++e) {
      float fv = (e < 4) ? f2lo[e] : f2hi[e - 4];
      float s0 = f1a + fv;
      s0 = fmaxf(s0, 0.2f * s0);                 // LeakyReLU (scaled domain)
      float q0 = __builtin_amdgcn_exp2f(s0);
      int k0 = ((int)(w0 << (31 - e))) >> 31;    // bit e -> 0 / 0xFFFFFFFF
      p0[e] = __uint_as_float(__float_as_uint(q0) & (unsigned)k0);

      float s1 = f1b + fv;
      s1 = fmaxf(s1, 0.2f * s1);
      float q1 = __builtin_amdgcn_exp2f(s1);
      int k1 = ((int)(w1 << (31 - e))) >> 31;
      p1v[e] = __uint_as_float(__float_as_uint(q1) & (unsigned)k1);
    }

    bf16x8 pb0, pb1;
#pragma unroll
    for (int e = 0; e < 8; ++e) {
      pb0[e] = (__bf16)p0[e];
      pb1[e] = (__bf16)p1v[e];
    }

#pragma unroll
    for (int c = 0; c < 4; ++c) {
      acc[c][0] = __builtin_amdgcn_mfma_f32_16x16x32_bf16(af[c], pb0, acc[c][0], 0, 0, 0);
      acc[c][1] = __builtin_amdgcn_mfma_f32_16x16x32_bf16(af[c], pb1, acc[c][1], 0, 0, 0);
    }
    acc[4][0] = __builtin_amdgcn_mfma_f32_16x16x32_bf16(ones, pb0, acc[4][0], 0, 0, 0);
    acc[4][1] = __builtin_amdgcn_mfma_f32_16x16x32_bf16(ones, pb1, acc[4][1], 0, 0, 0);
  }

  // ---- epilogue: combine the two m-halves, divide by denominator, sigmoid
  if (mhalf == 1) {
#pragma unroll
    for (int c = 0; c < 5; ++c)
#pragma unroll
      for (int j = 0; j < 2; ++j)
        *(f32x4*)(&ebuf[head][lane][(c * 2 + j) * 4]) = acc[c][j];
  }
  __syncthreads();
  if (mhalf == 0) {
    const float* eb = &ebuf[head][lane][0];
#pragma unroll
    for (int j = 0; j < 2; ++j) {
      float L = acc[4][j][0] + eb[(4 * 2 + j) * 4];
      float invL = 1.0f / L;
      const int nrow = n0 + j * 16 + il;
#pragma unroll
      for (int c = 0; c < 4; ++c) {
        f32x4 v;
#pragma unroll
        for (int r2 = 0; r2 < 4; ++r2) {
          float z = (acc[c][j][r2] + eb[(c * 2 + j) * 4 + r2]) * invL;
          v[r2] = 1.0f / (1.0f + __builtin_amdgcn_exp2f(-z * LOG2E));
        }
        // D layout: col = lane&15 (= n), row = kg*4 + r2 (= output feature)
        *(f32x4*)(out + (long)nrow * (NHEAD * FOUT) + head * FOUT + c * 16 + kg * 4) = v;
      }
    }
  }
}

extern "C" void kernel_launch(void* const* d_in, const int* in_sizes, int n_in,
                              void* d_out, int out_size, void* d_ws, size_t ws_size,
                              hipStream_t stream) {
  const float* x  = (const float*)d_in[0];
  const int*   adj= (const int*)d_in[1];
  const float* W  = (const float*)d_in[2];
  const float* a1 = (const float*)d_in[3];
  const float* a2 = (const float*)d_in[4];
  float* out = (float*)d_out;

  char* ws = (char*)d_ws;
  __hip_bfloat16* hT = (__hip_bfloat16*)ws;                         // 4 MB
  float* f1 = (float*)(ws + (size_t)NHEAD * FOUT * NROW * 2);       // 128 KB
  float* f2 = f1 + NHEAD * NROW;                                    // 128 KB

  gat_proj<<<NROW / 8, 256, 0, stream>>>(x, W, a1, a2, hT, f1, f2);
  gat_attn<<<NROW / 32, 512, 0, stream>>>(adj, hT, f1, f2, out);
}

// Round 2
// 237.909 us; speedup vs baseline: 1.7718x; 1.7718x over previous
//
#include <hip/hip_runtime.h>
#include <hip/hip_bf16.h>

#define NROW 8192
#define FIN  512
#define FOUT 64
#define NHEAD 4

constexpr float LOG2E = 1.44269504088896f;

typedef float f32x4 __attribute__((ext_vector_type(4)));
typedef __bf16 bf16x8 __attribute__((ext_vector_type(8)));

// ---------------------------------------------------------------------------
// K0: WT[hd][o][f] = bf16(W[hd][f][o])  (tiny transpose for MFMA A-frags)
// ---------------------------------------------------------------------------
__global__ __launch_bounds__(256) void wt_build(
    const float* __restrict__ W, __hip_bfloat16* __restrict__ WT)
{
  int t = blockIdx.x * 256 + threadIdx.x;       // 2048 threads = 4 heads x 512 f
  int hd = t >> 9, f = t & 511;
  const float* wp = W + (hd * FIN + f) * FOUT;
#pragma unroll 8
  for (int o = 0; o < FOUT; ++o)
    WT[(hd * FOUT + o) * FIN + f] = __float2bfloat16(wp[o]);
}

// ---------------------------------------------------------------------------
// K1: h = x*W via MFMA.  Wave = head; block = 4 heads sharing a 16-row n-tile.
// A = WT rows (i=o), B = bf16(x) (j=n), D: col(lane&15)=n, row(kg*4+r)=o.
// Epilogue: hT[o][n] bf16, f1/f2 = (h.a1/2)*LOG2E from f32 acc.
// ---------------------------------------------------------------------------
__global__ __launch_bounds__(256) void gat_proj(
    const float* __restrict__ x, const __hip_bfloat16* __restrict__ WT,
    const float* __restrict__ a1, const float* __restrict__ a2,
    __hip_bfloat16* __restrict__ hT, float* __restrict__ f1,
    float* __restrict__ f2)
{
  const int tid = threadIdx.x;
  const int hd = tid >> 6, lane = tid & 63;
  const int il = lane & 15, kg = lane >> 4;
  const int n0 = blockIdx.x * 16;
  const __hip_bfloat16* wtp = WT + hd * (FOUT * FIN);
  const float* xp = x + (n0 + il) * FIN + kg * 8;

  f32x4 acc[4];
#pragma unroll
  for (int c = 0; c < 4; ++c) { f32x4 z = {0.f,0.f,0.f,0.f}; acc[c] = z; }

#pragma unroll 2
  for (int kk = 0; kk < FIN / 32; ++kk) {
    bf16x8 af[4];
#pragma unroll
    for (int c = 0; c < 4; ++c)
      af[c] = *(const bf16x8*)(wtp + (c * 16 + il) * FIN + kk * 32 + kg * 8);
    f32x4 xl = *(const f32x4*)(xp + kk * 32);
    f32x4 xh = *(const f32x4*)(xp + kk * 32 + 4);
    bf16x8 xb;
#pragma unroll
    for (int e = 0; e < 4; ++e) {
      xb[e]     = (__bf16)xl[e];
      xb[4 + e] = (__bf16)xh[e];
    }
#pragma unroll
    for (int c = 0; c < 4; ++c)
      acc[c] = __builtin_amdgcn_mfma_f32_16x16x32_bf16(af[c], xb, acc[c], 0, 0, 0);
  }

  const int n = n0 + il;
  float p1 = 0.f, p2 = 0.f;
#pragma unroll
  for (int c = 0; c < 4; ++c) {
    f32x4 a1v = *(const f32x4*)(a1 + hd * FOUT + c * 16 + kg * 4);
    f32x4 a2v = *(const f32x4*)(a2 + hd * FOUT + c * 16 + kg * 4);
#pragma unroll
    for (int r = 0; r < 4; ++r) {
      float hv = acc[c][r];
      hT[(hd * FOUT + c * 16 + kg * 4 + r) * NROW + n] = __float2bfloat16(hv);
      p1 = fmaf(hv, a1v[r], p1);
      p2 = fmaf(hv, a2v[r], p2);
    }
  }
  p1 += __shfl_xor(p1, 16); p1 += __shfl_xor(p1, 32);
  p2 += __shfl_xor(p2, 16); p2 += __shfl_xor(p2, 32);
  if (kg == 0) {
    f1[hd * NROW + n] = p1 * LOG2E;
    f2[hd * NROW + n] = p2 * LOG2E;
  }
}

// ---------------------------------------------------------------------------
// K2: pack adj into bitmasks  mw[w = m/32][n]  (bit b of word w <-> m = w*32+b)
// wave = one row, coalesced 64-int reads, ballot, lane0 writes 2 words.
// ---------------------------------------------------------------------------
__global__ __launch_bounds__(256) void mask_build(
    const int* __restrict__ adj, unsigned int* __restrict__ mw)
{
  const int wid = threadIdx.x >> 6, lane = threadIdx.x & 63;
  const int nrow = blockIdx.x * 4 + wid;
  const int* ap = adj + (size_t)nrow * NROW;
#pragma unroll 2
  for (int it = 0; it < NROW / 64; ++it) {
    unsigned long long b = __ballot(ap[it * 64 + lane] != 0);
    if (lane == 0) {
      mw[(it * 2) * NROW + nrow]     = (unsigned int)b;
      mw[(it * 2 + 1) * NROW + nrow] = (unsigned int)(b >> 32);
    }
  }
}

// ---------------------------------------------------------------------------
// K3: attention partials. Block = 4 waves, SAME head, 64 rows (16/wave),
// m-chunk of NROW/S. hT tile [64 o][64 m] staged in padded LDS (stride 72
// elems = 144B -> conflict-free-ish), reg-staged + double-buffered, one
// barrier/iter. Masks from mw, f2 direct (L2-hot). Partial num (64 o) +
// denom (ones-MFMA) per (mchunk, head, row) -> part[.][n][68].
// ---------------------------------------------------------------------------
template <int S>
__global__ __launch_bounds__(256, 4) void gat_attn(
    const unsigned int* __restrict__ mw, const __hip_bfloat16* __restrict__ hTg,
    const float* __restrict__ f1, const float* __restrict__ f2,
    float* __restrict__ part)
{
  constexpr int MCH = NROW / S;
  constexpr int ITERS = MCH / 64;
  const int tid = threadIdx.x;
  const int wid = tid >> 6, lane = tid & 63;
  const int il = lane & 15, kg = lane >> 4;
  const int bid = blockIdx.x;
  const int rg = bid & 127;
  const int hd = (bid >> 7) & 3;
  const int mc = bid >> 9;
  const int n0 = rg * 64;
  const int n  = n0 + wid * 16 + il;
  const int mbase = mc * MCH;

  __shared__ __align__(16) __hip_bfloat16 lds[2][64 * 72];

  const float f1a = f1[hd * NROW + n];
  const float* f2p = f2 + hd * NROW + mbase;
  const unsigned int* mwp = mw + (size_t)(mc * (MCH / 32)) * NROW + n;
  const __hip_bfloat16* hsrc =
      hTg + ((hd * FOUT) + (tid >> 2)) * NROW + mbase + (tid & 3) * 16;
  const int lof = (tid >> 2) * 72 + (tid & 3) * 16;   // element offset in tile

  f32x4 acc[5];
#pragma unroll
  for (int c = 0; c < 5; ++c) { f32x4 z = {0.f,0.f,0.f,0.f}; acc[c] = z; }

  bf16x8 ones;
#pragma unroll
  for (int e = 0; e < 8; ++e) ones[e] = (__bf16)1.0f;

  // prologue: stage tile 0
  {
    bf16x8 s0 = *(const bf16x8*)(hsrc);
    bf16x8 s1 = *(const bf16x8*)(hsrc + 8);
    *(bf16x8*)(&lds[0][lof])     = s0;
    *(bf16x8*)(&lds[0][lof + 8]) = s1;
  }
  __syncthreads();

  for (int it = 0; it < ITERS; ++it) {
    const int cur = it & 1;
    bf16x8 s0n, s1n;
    const bool more = (it + 1 < ITERS);
    if (more) {                       // issue next-tile loads early (T14)
      s0n = *(const bf16x8*)(hsrc + (it + 1) * 64);
      s1n = *(const bf16x8*)(hsrc + (it + 1) * 64 + 8);
    }

#pragma unroll
    for (int ks = 0; ks < 2; ++ks) {
      unsigned int mvs = mwp[(it * 2 + ks) * NROW] >> (kg * 8);
      f32x4 fvl = *(const f32x4*)(f2p + it * 64 + ks * 32 + kg * 8);
      f32x4 fvh = *(const f32x4*)(f2p + it * 64 + ks * 32 + kg * 8 + 4);

      bf16x8 afr[4];
#pragma unroll
      for (int c = 0; c < 4; ++c)
        afr[c] = *(const bf16x8*)(&lds[cur][(c * 16 + il) * 72 + ks * 32 + kg * 8]);

      float p[8];
#pragma unroll
      for (int e = 0; e < 8; ++e) {
        float fv = (e < 4) ? fvl[e] : fvh[e - 4];
        float s = f1a + fv;
        s = fmaxf(s, 0.2f * s);                    // LeakyReLU (scaled domain)
        float q = __builtin_amdgcn_exp2f(s);
        int msk = ((int)(mvs << (31 - e))) >> 31;  // bit e -> 0 / -1
        p[e] = __uint_as_float(__float_as_uint(q) & (unsigned)msk);
      }
      bf16x8 pb;
#pragma unroll
      for (int e = 0; e < 8; ++e) pb[e] = (__bf16)p[e];

#pragma unroll
      for (int c = 0; c < 4; ++c)
        acc[c] = __builtin_amdgcn_mfma_f32_16x16x32_bf16(afr[c], pb, acc[c], 0, 0, 0);
      acc[4] = __builtin_amdgcn_mfma_f32_16x16x32_bf16(ones, pb, acc[4], 0, 0, 0);
    }

    if (more) {
      *(bf16x8*)(&lds[cur ^ 1][lof])     = s0n;
      *(bf16x8*)(&lds[cur ^ 1][lof + 8]) = s1n;
      __syncthreads();
    }
  }

  // partials: [mc*NHEAD+hd][n][68]  (0..63 num, 64 denom, 65..67 pad)
  float* pp = part + ((size_t)((mc * NHEAD + hd) * NROW + n)) * 68;
#pragma unroll
  for (int c = 0; c < 4; ++c)
    *(f32x4*)(pp + c * 16 + kg * 4) = acc[c];
  if (kg == 0) pp[64] = acc[4][0];
}

// ---------------------------------------------------------------------------
// K4: combine S partial slices, divide, sigmoid, write out.
// ---------------------------------------------------------------------------
__global__ __launch_bounds__(256) void gat_comb(
    const float* __restrict__ part, float* __restrict__ out, int S)
{
  int flat = blockIdx.x * 256 + threadIdx.x;
  int n = flat >> 6, c4 = flat & 63;
  int hd = c4 >> 4, o4 = (c4 & 15) * 4;
  f32x4 num = {0.f,0.f,0.f,0.f};
  float L = 0.f;
  for (int s = 0; s < S; ++s) {
    const float* pp = part + ((size_t)((s * NHEAD + hd) * NROW + n)) * 68;
    f32x4 v = *(const f32x4*)(pp + o4);
    num += v;
    L += pp[64];
  }
  float invL = 1.0f / L;
  f32x4 r;
#pragma unroll
  for (int j = 0; j < 4; ++j)
    r[j] = 1.0f / (1.0f + __builtin_amdgcn_exp2f(-num[j] * invL * LOG2E));
  *(f32x4*)(out + (size_t)n * (NHEAD * FOUT) + hd * FOUT + o4) = r;
}

extern "C" void kernel_launch(void* const* d_in, const int* in_sizes, int n_in,
                              void* d_out, int out_size, void* d_ws, size_t ws_size,
                              hipStream_t stream) {
  const float* x   = (const float*)d_in[0];
  const int*   adj = (const int*)d_in[1];
  const float* W   = (const float*)d_in[2];
  const float* a1  = (const float*)d_in[3];
  const float* a2  = (const float*)d_in[4];
  float* out = (float*)d_out;

  char* ws = (char*)d_ws;
  const size_t WT_OFF = 0;
  const size_t HT_OFF = WT_OFF + (size_t)NHEAD * FOUT * FIN * 2;     // 256 KB
  const size_t F1_OFF = HT_OFF + (size_t)NHEAD * FOUT * NROW * 2;    // 4 MB
  const size_t F2_OFF = F1_OFF + (size_t)NHEAD * NROW * 4;
  const size_t MW_OFF = F2_OFF + (size_t)NHEAD * NROW * 4;
  const size_t PT_OFF = MW_OFF + (size_t)(NROW / 32) * NROW * 4;     // 8 MB
  const size_t PART_SLICE = (size_t)NHEAD * NROW * 68 * 4;           // 8.9 MB

  int S = (ws_size >= PT_OFF + 2 * PART_SLICE) ? 2 : 1;

  __hip_bfloat16* WT = (__hip_bfloat16*)(ws + WT_OFF);
  __hip_bfloat16* hT = (__hip_bfloat16*)(ws + HT_OFF);
  float* f1 = (float*)(ws + F1_OFF);
  float* f2 = (float*)(ws + F2_OFF);
  unsigned int* mw = (unsigned int*)(ws + MW_OFF);
  float* part = (float*)(ws + PT_OFF);

  wt_build<<<8, 256, 0, stream>>>(W, WT);
  mask_build<<<NROW / 4, 256, 0, stream>>>(adj, mw);
  gat_proj<<<NROW / 16, 256, 0, stream>>>(x, WT, a1, a2, hT, f1, f2);
  if (S == 2)
    gat_attn<2><<<2 * NHEAD * 128, 256, 0, stream>>>(mw, hT, f1, f2, part);
  else
    gat_attn<1><<<1 * NHEAD * 128, 256, 0, stream>>>(mw, hT, f1, f2, part);
  gat_comb<<<NROW * NHEAD * FOUT / 4 / 256, 256, 0, stream>>>(part, out, S);
}